// Round 8
// baseline (376.857 us; speedup 1.0000x reference)
//
#include <hip/hip_runtime.h>

// Retrace loss: T=8192, K=2048, gamma=0.99.
// decay = cumprod(gamma*iw); S = reverse-cumsum(td*decay);
// retrace = S / max(decay,1e-10); loss = mean(smooth_l1(q, retrace)).
//
// f32 decay underflows to EXACT 0 within ~170 rows for every column
// (E[ln c]=-0.574, sd 0.83/step; at row 512 log-decay = -294 +- 18.7, vs
// f32 denorm floor ln~=-103 => alive prob ~1e-24). Once decay==0,
// retrace==0 in both our and the reference's arithmetic (absmax 0.0,
// rounds 6-7).
//
// R7 lesson: co-scheduling the latency-bound prefix chain with the tail
// BW flood stretched the chain 5x (52->74.5us). R8 restores R6's
// serialization but cuts structure:
//   kPre   : ALONE. rows [0,512) in 8x256 LDS tiles (512 blocks, 2/CU),
//            writes packed bf16 (y|ld) + chunk summaries P,Zl; inits ctrl.
//   kApply : role A: apply with INLINE chunk scan (P/Zl L2-hot);
//            role B: unconditional tail sum sl1(sv), rows [512,8191);
//            role C: exact serial fallback per alive column (never taken
//            for this data; subtracts role-B's assumed terms);
//            ticket: last block writes the mean. No kScan, no k4.

#define GAMMA 0.99f

constexpr int T_ = 8192;
constexpr int K_ = 2048;
constexpr int N_ = T_ - 1;               // 8191
constexpr int MROWS = 512;               // exact-prefix length
constexpr int L_ = 8;                    // rows per chunk
constexpr int MCH = MROWS / L_;          // 64 chunks
constexpr int NBPRE = MCH * (K_ / 256);  // 512 blocks (roles P and A)
constexpr int NBTAIL = 2048;             // role-B blocks
constexpr int NBFALL = K_;               // role-C blocks (one per column)
constexpr long long TAILF4 = (long long)(N_ - MROWS) * K_ / 4;  // 3,931,648

typedef float f4 __attribute__((ext_vector_type(4)));
typedef unsigned short us4 __attribute__((ext_vector_type(4)));

__device__ __forceinline__ unsigned short f2bf(float f) {  // RTNE
  unsigned u = __float_as_uint(f);
  u += 0x7FFFu + ((u >> 16) & 1u);
  return (unsigned short)(u >> 16);
}
__device__ __forceinline__ float bf2f(unsigned short h) {
  return __uint_as_float(((unsigned)h) << 16);
}
__device__ __forceinline__ float bfhi(unsigned q) {  // y in hi16
  return __uint_as_float(q & 0xFFFF0000u);
}
__device__ __forceinline__ float bflo(unsigned q) {  // ld in lo16
  return __uint_as_float(q << 16);
}
__device__ __forceinline__ float sl1(float dd) {
  float ad = fabsf(dd);
  return (ad < 1.f) ? 0.5f * dd * dd : ad - 0.5f;
}
__device__ __forceinline__ void block_reduce_add(float l, double* acc) {
  for (int off = 32; off > 0; off >>= 1) l += __shfl_down(l, off);
  __shared__ float wsum[4];
  const int lane = threadIdx.x & 63, wid = threadIdx.x >> 6;
  if (lane == 0) wsum[wid] = l;
  __syncthreads();
  if (threadIdx.x == 0) {
    float b = wsum[0] + wsum[1] + wsum[2] + wsum[3];
    if (b != 0.f) atomicAdd(acc, (double)b);
  }
}

// ---------------------------------------------------------------- kPre
// 8x256 tile of rows [0,512). Grid: 512 blocks (chunk = bid>>3, colblock
// = bid&7). Phase 1: waves stream 4 rows in parallel (depth-1 pipeline);
// phase 2: per-column f32 chain, packed bf16 store.
__global__ __launch_bounds__(256) void kPre(
    const float* __restrict__ tsv, const float* __restrict__ tev,
    const float* __restrict__ r, const float* __restrict__ ologp,
    const float* __restrict__ tlogp, unsigned* __restrict__ pkPre,
    float* __restrict__ P, float* __restrict__ Zl, double* __restrict__ acc,
    unsigned* __restrict__ done) {
  __shared__ float csh[L_][256];            // f32 c (exact chain)
  __shared__ unsigned short tdsh[L_][256];  // bf16 td
  const int tid = threadIdx.x;
  const int lane = tid & 63;
  const int wid = tid >> 6;
  const int c0 = (blockIdx.x & 7) * 256;
  const int chunk = blockIdx.x >> 3;
  const int i0 = chunk * L_;
  const int col = c0 + lane * 4;

  // phase 1: wave w handles rows w and w+4
  f4 lwA, aA, vA, rrA;
  float oA;
  auto issue = [&](int s, f4& lw, f4& a, f4& v, f4& rr, float& o) {
    const int i = i0 + s;
    const size_t b1 = (size_t)(i + 1) * K_ + col;
    const size_t b0 = (size_t)i * K_ + col;
    lw = *(const f4*)(tlogp + b1);
    a = *(const f4*)(tsv + b1);
    v = *(const f4*)(tev + b1);
    rr = *(const f4*)(r + b0);
    o = ologp[i + 1];
  };
  issue(wid, lwA, aA, vA, rrA, oA);
#pragma unroll
  for (int s0 = 0; s0 < L_; s0 += 4) {
    const int s = s0 + wid;
    f4 lwB, aB, vB, rrB;
    float oB;
    if (s0 + 4 < L_) issue(s + 4, lwB, aB, vB, rrB, oB);
    __builtin_amdgcn_sched_barrier(0);
    f4 iw, c, td;
#pragma unroll
    for (int x = 0; x < 4; ++x) iw[x] = __expf(fminf(lwA[x] - oA, 0.f));
#pragma unroll
    for (int x = 0; x < 4; ++x) c[x] = GAMMA * iw[x];
#pragma unroll
    for (int x = 0; x < 4; ++x)
      td[x] = fmaf(GAMMA, fmaf(-iw[x], aA[x], vA[x]), rrA[x]);
    *(f4*)&csh[s][lane * 4] = c;
    us4 t4;
#pragma unroll
    for (int x = 0; x < 4; ++x) t4[x] = f2bf(td[x]);
    *(us4*)&tdsh[s][lane * 4] = t4;
    if (s0 + 4 < L_) {
      lwA = lwB;
      aA = aB;
      vA = vB;
      rrA = rrB;
      oA = oB;
    }
  }
  __syncthreads();

  // phase 2: per-column f32 chain, store packed y|ld
  const int kcol = c0 + tid;
  float p = 1.f, zl = 0.f;
#pragma unroll
  for (int s = 0; s < L_; ++s) {
    p *= csh[s][tid];
    float y = bf2f(tdsh[s][tid]) * p;
    zl += y;
    pkPre[(size_t)(i0 + s) * K_ + kcol] = ((unsigned)f2bf(y) << 16) | f2bf(p);
  }
  P[(size_t)chunk * K_ + kcol] = p;
  Zl[(size_t)chunk * K_ + kcol] = zl;

  if (blockIdx.x == 0 && tid == 0) {  // init ctrl (no acc user until next
    *acc = 0.0;                       //  launch -> race-free)
    *done = 0u;
  }
}

// ---------------------------------------------------------------- kApply
__global__ __launch_bounds__(256) void kApply(
    const float* __restrict__ sv, const float* __restrict__ tsv,
    const float* __restrict__ tev, const float* __restrict__ r,
    const float* __restrict__ ologp, const float* __restrict__ tlogp,
    const unsigned* __restrict__ pkPre, const float* __restrict__ P,
    const float* __restrict__ Zl, unsigned* __restrict__ pkFull,
    double* __restrict__ acc, unsigned* __restrict__ done,
    float* __restrict__ out) {
  const int bid = blockIdx.x;
  const int tid = threadIdx.x;

  if (bid < NBPRE) {  // ---- role A: prefix apply, inline chunk scan
    const int myc = bid >> 3;
    const int k = (bid & 7) * 256 + tid;
    // d0 = prod_{c<myc} P_c ; dj = full product (alive test)
    float d0 = 1.f, dj = 1.f;
    for (int c = 0; c < MCH; ++c) {
      if (c == myc) d0 = dj;
      dj *= P[(size_t)c * K_ + k];
    }
    float loss = 0.f;
    if (dj == 0.f) {  // dead column: chunked-scan result is exact
      float ssuf = 0.f;
      float dp = d0 * P[(size_t)myc * K_ + k];
      for (int c = myc + 1; c < MCH; ++c) {
        ssuf = fmaf(dp, Zl[(size_t)c * K_ + k], ssuf);
        dp *= P[(size_t)c * K_ + k];
      }
      const int i0 = myc * L_;
      float slocal = 0.f;
#pragma unroll
      for (int s = L_ - 1; s >= 0; --s) {
        const size_t b0 = (size_t)(i0 + s) * K_ + k;
        unsigned q = pkPre[b0];
        slocal += bfhi(q);
        float S = fmaf(d0, slocal, ssuf);
        float retrace = S / fmaxf(d0 * bflo(q), 1e-10f);
        loss += sl1(sv[b0] - retrace);
      }
    }
    block_reduce_add(loss, acc);
  } else if (bid < NBPRE + NBTAIL) {  // ---- role B: tail rows [512,8191)
    const long long base = (long long)MROWS * K_ / 4;  // f4 offset
    float loss = 0.f;
    for (long long v = (long long)(bid - NBPRE) * 256 + tid; v < TAILF4;
         v += (long long)NBTAIL * 256) {
      f4 q = ((const f4*)sv)[base + v];
#pragma unroll
      for (int x = 0; x < 4; ++x) loss += sl1(q[x]);
    }
    block_reduce_add(loss, acc);
  } else {  // ---- role C: exact fallback for alive columns (rare/never)
    const int col = bid - NBPRE - NBTAIL;
    if (tid == 0) {
      float dj = 1.f;
      for (int c = 0; c < MCH; ++c) dj *= P[(size_t)c * K_ + col];
      if (dj != 0.f) {  // alive: recompute the whole column exactly
        unsigned* mycol = pkFull + (size_t)col * 8192;
        float p = 1.f;
        for (int i = 0; i < N_; ++i) {  // forward: exact sequential decay
          const size_t b1 = (size_t)(i + 1) * K_ + col;
          float iw = __expf(fminf(tlogp[b1] - ologp[i + 1], 0.f));
          p *= GAMMA * iw;
          float td = fmaf(GAMMA, fmaf(-iw, tsv[b1], tev[b1]),
                          r[(size_t)i * K_ + col]);
          mycol[i] = ((unsigned)f2bf(td * p) << 16) | f2bf(p);
        }
        float slocal = 0.f, loss = 0.f;
        for (int i = N_ - 1; i >= 0; --i) {  // backward: S, loss, tail undo
          unsigned q = mycol[i];
          slocal += bfhi(q);
          float retrace = slocal / fmaxf(bflo(q), 1e-10f);
          float qv = sv[(size_t)i * K_ + col];
          loss += sl1(qv - retrace);
          if (i >= MROWS) loss -= sl1(qv);  // role B already added this
        }
        // role A also added chunked-scan terms for this column? No: role A
        // only adds when dj==0, so alive columns got nothing from A.
        atomicAdd(acc, (double)loss);
      }
    }
  }

  // ---- ticket: last block publishes the mean
  __threadfence();
  if (tid == 0) {
    const unsigned prev = atomicAdd(done, 1u);
    if (prev == (unsigned)(NBPRE + NBTAIL + NBFALL) - 1u) {
      __threadfence();
      out[0] = (float)(*acc * (1.0 / ((double)N_ * (double)K_)));
    }
  }
}

extern "C" void kernel_launch(void* const* d_in, const int* in_sizes, int n_in,
                              void* d_out, int out_size, void* d_ws,
                              size_t ws_size, hipStream_t stream) {
  const float* sv = (const float*)d_in[0];
  const float* tsv = (const float*)d_in[1];
  const float* tev = (const float*)d_in[2];
  const float* r = (const float*)d_in[3];
  const float* ologp = (const float*)d_in[4];
  const float* tlogp = (const float*)d_in[5];

  // ws layout (~72 MB; harness provided >= 75.5 MB in rounds 2-7)
  char* w = (char*)d_ws;
  double* acc = (double*)w;  // ctrl: acc(8) + done(4)
  unsigned* done = (unsigned*)(w + 8);
  w += 256;
  unsigned* pkPre = (unsigned*)w;  // 512*2048*4 = 4 MB
  w += (size_t)MROWS * K_ * 4;
  float* P = (float*)w;  // 64*2048*4 = 512 KB
  w += (size_t)MCH * K_ * 4;
  float* Zl = (float*)w;
  w += (size_t)MCH * K_ * 4;
  unsigned* pkFull = (unsigned*)w;  // 2048*8192*4 = 67 MB (fallback only)

  kPre<<<NBPRE, 256, 0, stream>>>(tsv, tev, r, ologp, tlogp, pkPre, P, Zl,
                                  acc, done);
  kApply<<<NBPRE + NBTAIL + NBFALL, 256, 0, stream>>>(
      sv, tsv, tev, r, ologp, tlogp, pkPre, P, Zl, pkFull, acc, done,
      (float*)d_out);
}

// Round 9
// 77.072 us; speedup vs baseline: 4.8897x; 4.8897x over previous
//
#include <hip/hip_runtime.h>

// Retrace loss: T=8192, K=2048, gamma=0.99.
// decay = cumprod(gamma*iw); S = reverse-cumsum(td*decay);
// retrace = S / max(decay,1e-10); loss = mean(smooth_l1(q, retrace)).
//
// f32 decay underflows to EXACT 0 within ~170 rows for every column
// (E[ln c]=-0.574, sd 0.83/step; at row 512 log-decay = -294 +- 18.7 =>
// alive prob ~1e-24). Once decay==0, retrace==0 in both our and the
// reference's arithmetic (absmax 0.0, rounds 6-8).
//
// Structure lessons (hard-won):
//  R7: co-scheduling the latency-bound prefix chain with the tail BW flood
//      stretches the chain 5x. Keep kPre ALONE.
//  R8: __threadfence() ticket in a 4608-block grid = L2 writeback/invalidate
//      storm on non-coherent-L2 gfx950: 448us at 1% VALU. NO device fences;
//      use the R1-R6-proven plain-init -> atomicAdd -> separate-launch-read
//      pattern instead.
// R9 = R6's proven 4-launch shape + R8's proven kPre (L=8, 512 blocks).

#define GAMMA 0.99f

constexpr int T_ = 8192;
constexpr int K_ = 2048;
constexpr int N_ = T_ - 1;               // 8191
constexpr int MROWS = 512;               // exact-prefix length
constexpr int L_ = 8;                    // rows per chunk
constexpr int MCH = MROWS / L_;          // 64 chunks
constexpr int NBPRE = MCH * (K_ / 256);  // 512 blocks (kPre and role A)
constexpr int NBTAIL = 2048;             // role-B blocks
constexpr int NBC = K_ / 256;            // 8 role-C blocks
constexpr long long TAILF4 = (long long)(N_ - MROWS) * K_ / 4;  // 3,931,648

typedef float f4 __attribute__((ext_vector_type(4)));
typedef unsigned short us4 __attribute__((ext_vector_type(4)));

__device__ __forceinline__ unsigned short f2bf(float f) {  // RTNE
  unsigned u = __float_as_uint(f);
  u += 0x7FFFu + ((u >> 16) & 1u);
  return (unsigned short)(u >> 16);
}
__device__ __forceinline__ float bf2f(unsigned short h) {
  return __uint_as_float(((unsigned)h) << 16);
}
__device__ __forceinline__ float bfhi(unsigned q) {  // y in hi16
  return __uint_as_float(q & 0xFFFF0000u);
}
__device__ __forceinline__ float bflo(unsigned q) {  // ld in lo16
  return __uint_as_float(q << 16);
}
__device__ __forceinline__ float sl1(float dd) {
  float ad = fabsf(dd);
  return (ad < 1.f) ? 0.5f * dd * dd : ad - 0.5f;
}
__device__ __forceinline__ void block_reduce_add(float l, double* acc) {
  for (int off = 32; off > 0; off >>= 1) l += __shfl_down(l, off);
  __shared__ float wsum[4];
  const int lane = threadIdx.x & 63, wid = threadIdx.x >> 6;
  if (lane == 0) wsum[wid] = l;
  __syncthreads();
  if (threadIdx.x == 0) {
    float b = wsum[0] + wsum[1] + wsum[2] + wsum[3];
    if (b != 0.f) atomicAdd(acc, (double)b);
  }
}

// ---------------------------------------------------------------- kPre
// 8x256 tile of rows [0,512). Grid: 512 blocks (chunk = bid>>3, colblock
// = bid&7). Phase 1: waves stream rows (depth-1 pipeline, no chain near
// loads); phase 2: per-column f32 chain, packed bf16 (y|ld) store +
// chunk summaries P, Zl. Proven in R8 (absmax 0.0).
__global__ __launch_bounds__(256) void kPre(
    const float* __restrict__ tsv, const float* __restrict__ tev,
    const float* __restrict__ r, const float* __restrict__ ologp,
    const float* __restrict__ tlogp, unsigned* __restrict__ pkPre,
    float* __restrict__ P, float* __restrict__ Zl, double* __restrict__ acc,
    unsigned* __restrict__ flagbits, unsigned* __restrict__ nAlive) {
  __shared__ float csh[L_][256];            // f32 c (exact chain)
  __shared__ unsigned short tdsh[L_][256];  // bf16 td
  const int tid = threadIdx.x;
  const int lane = tid & 63;
  const int wid = tid >> 6;
  const int c0 = (blockIdx.x & 7) * 256;
  const int chunk = blockIdx.x >> 3;
  const int i0 = chunk * L_;
  const int col = c0 + lane * 4;

  f4 lwA, aA, vA, rrA;
  float oA;
  auto issue = [&](int s, f4& lw, f4& a, f4& v, f4& rr, float& o) {
    const int i = i0 + s;
    const size_t b1 = (size_t)(i + 1) * K_ + col;
    const size_t b0 = (size_t)i * K_ + col;
    lw = *(const f4*)(tlogp + b1);
    a = *(const f4*)(tsv + b1);
    v = *(const f4*)(tev + b1);
    rr = *(const f4*)(r + b0);
    o = ologp[i + 1];
  };
  issue(wid, lwA, aA, vA, rrA, oA);
#pragma unroll
  for (int s0 = 0; s0 < L_; s0 += 4) {
    const int s = s0 + wid;
    f4 lwB, aB, vB, rrB;
    float oB;
    if (s0 + 4 < L_) issue(s + 4, lwB, aB, vB, rrB, oB);
    __builtin_amdgcn_sched_barrier(0);
    f4 iw, c, td;
#pragma unroll
    for (int x = 0; x < 4; ++x) iw[x] = __expf(fminf(lwA[x] - oA, 0.f));
#pragma unroll
    for (int x = 0; x < 4; ++x) c[x] = GAMMA * iw[x];
#pragma unroll
    for (int x = 0; x < 4; ++x)
      td[x] = fmaf(GAMMA, fmaf(-iw[x], aA[x], vA[x]), rrA[x]);
    *(f4*)&csh[s][lane * 4] = c;
    us4 t4;
#pragma unroll
    for (int x = 0; x < 4; ++x) t4[x] = f2bf(td[x]);
    *(us4*)&tdsh[s][lane * 4] = t4;
    if (s0 + 4 < L_) {
      lwA = lwB;
      aA = aB;
      vA = vB;
      rrA = rrB;
      oA = oB;
    }
  }
  __syncthreads();

  const int kcol = c0 + tid;
  float p = 1.f, zl = 0.f;
#pragma unroll
  for (int s = 0; s < L_; ++s) {
    p *= csh[s][tid];
    float y = bf2f(tdsh[s][tid]) * p;
    zl += y;
    pkPre[(size_t)(i0 + s) * K_ + kcol] = ((unsigned)f2bf(y) << 16) | f2bf(p);
  }
  P[(size_t)chunk * K_ + kcol] = p;
  Zl[(size_t)chunk * K_ + kcol] = zl;

  if (blockIdx.x == 0) {  // init ctrl; consumed only by later launches
    if (tid < 64) flagbits[tid] = 0u;
    if (tid == 64) *nAlive = 0u;
    if (tid == 65) *acc = 0.0;
  }
}

// ---------------------------------------------------------------- kScan
// Per column: chunk prefix products D0, suffix sums Ssuf, alive flag.
__global__ __launch_bounds__(256) void kScan(
    const float* __restrict__ P, const float* __restrict__ Zl,
    float* __restrict__ D0, float* __restrict__ Ssuf,
    unsigned* __restrict__ flagbits, unsigned* __restrict__ nAlive) {
  const int k = blockIdx.x * 256 + threadIdx.x;  // 0..K-1
  float d = 1.f;
#pragma unroll 16
  for (int c = 0; c < MCH; ++c) {
    D0[(size_t)c * K_ + k] = d;
    d *= P[(size_t)c * K_ + k];
  }
  if (d != 0.f) {  // alive: prefix decay survived 512 rows (never, typ.)
    atomicOr(&flagbits[k >> 5], 1u << (k & 31));
    atomicAdd(nAlive, 1u);
  }
  float ss = 0.f;
#pragma unroll 16
  for (int c = MCH - 1; c >= 0; --c) {
    Ssuf[(size_t)c * K_ + k] = ss;
    ss = fmaf(D0[(size_t)c * K_ + k], Zl[(size_t)c * K_ + k], ss);
  }
}

// ---------------------------------------------------------------- kApply
// Role A: prefix apply (D0/Ssuf precomputed). Role B: tail sl1(sv) for
// dead columns. Role C: exact serial fallback per alive column.
// NO fences, NO ticket (R8 lesson).
__global__ __launch_bounds__(256) void kApply(
    const float* __restrict__ sv, const float* __restrict__ tsv,
    const float* __restrict__ tev, const float* __restrict__ r,
    const float* __restrict__ ologp, const float* __restrict__ tlogp,
    const unsigned* __restrict__ pkPre, const float* __restrict__ D0,
    const float* __restrict__ Ssuf, const unsigned* __restrict__ flagbits,
    const unsigned* __restrict__ nAlive, unsigned* __restrict__ pkFull,
    double* __restrict__ acc) {
  const int bid = blockIdx.x;
  const int tid = threadIdx.x;

  if (bid < NBPRE) {  // ---- role A: prefix rows [0,512)
    const int myc = bid >> 3;
    const int k = (bid & 7) * 256 + tid;
    float loss = 0.f;
    if (!((flagbits[k >> 5] >> (k & 31)) & 1u)) {
      const float d0 = D0[(size_t)myc * K_ + k];
      const float ssuf = Ssuf[(size_t)myc * K_ + k];
      const int i0 = myc * L_;
      float slocal = 0.f;
#pragma unroll
      for (int s = L_ - 1; s >= 0; --s) {
        const size_t b0 = (size_t)(i0 + s) * K_ + k;
        unsigned q = pkPre[b0];
        slocal += bfhi(q);
        float S = fmaf(d0, slocal, ssuf);
        float retrace = S / fmaxf(d0 * bflo(q), 1e-10f);
        loss += sl1(sv[b0] - retrace);
      }
    }
    block_reduce_add(loss, acc);
  } else if (bid < NBPRE + NBTAIL) {  // ---- role B: tail rows [512,8191)
    __shared__ unsigned fb[64];
    if (tid < 64) fb[tid] = flagbits[tid];
    __syncthreads();
    const unsigned nA = *nAlive;
    const long long base = (long long)MROWS * K_ / 4;  // f4 offset
    float loss = 0.f;
    if (nA == 0) {  // fast path: all columns dead
      for (long long v = (long long)(bid - NBPRE) * 256 + tid; v < TAILF4;
           v += (long long)NBTAIL * 256) {
        f4 q = ((const f4*)sv)[base + v];
#pragma unroll
        for (int x = 0; x < 4; ++x) loss += sl1(q[x]);
      }
    } else {
      for (long long v = (long long)(bid - NBPRE) * 256 + tid; v < TAILF4;
           v += (long long)NBTAIL * 256) {
        f4 q = ((const f4*)sv)[base + v];
        const int k0 = (int)((v * 4) & (K_ - 1));
#pragma unroll
        for (int x = 0; x < 4; ++x) {
          const int k = k0 + x;
          if (!((fb[k >> 5] >> (k & 31)) & 1u)) loss += sl1(q[x]);
        }
      }
    }
    block_reduce_add(loss, acc);
  } else {  // ---- role C: exact fallback, thread per column (rare/never)
    const int k = (bid - NBPRE - NBTAIL) * 256 + tid;
    if ((flagbits[k >> 5] >> (k & 31)) & 1u) {
      unsigned* mycol = pkFull + (size_t)k * 8192;
      float p = 1.f;
      for (int i = 0; i < N_; ++i) {  // forward: exact sequential decay
        const size_t b1 = (size_t)(i + 1) * K_ + k;
        float iw = __expf(fminf(tlogp[b1] - ologp[i + 1], 0.f));
        p *= GAMMA * iw;
        float td =
            fmaf(GAMMA, fmaf(-iw, tsv[b1], tev[b1]), r[(size_t)i * K_ + k]);
        mycol[i] = ((unsigned)f2bf(td * p) << 16) | f2bf(p);
      }
      float slocal = 0.f, loss = 0.f;
      for (int i = N_ - 1; i >= 0; --i) {  // backward: S, loss, tail undo
        unsigned q = mycol[i];
        slocal += bfhi(q);
        float retrace = slocal / fmaxf(bflo(q), 1e-10f);
        float qv = sv[(size_t)i * K_ + k];
        loss += sl1(qv - retrace);
        if (i >= MROWS) loss -= sl1(qv);  // role B already added this
      }
      atomicAdd(acc, (double)loss);  // role A skipped alive columns
    }
  }
}

// ---------------------------------------------------------------- k4
__global__ void k4(const double* __restrict__ acc, float* __restrict__ out) {
  out[0] = (float)(*acc * (1.0 / ((double)N_ * (double)K_)));
}

extern "C" void kernel_launch(void* const* d_in, const int* in_sizes, int n_in,
                              void* d_out, int out_size, void* d_ws,
                              size_t ws_size, hipStream_t stream) {
  const float* sv = (const float*)d_in[0];
  const float* tsv = (const float*)d_in[1];
  const float* tev = (const float*)d_in[2];
  const float* r = (const float*)d_in[3];
  const float* ologp = (const float*)d_in[4];
  const float* tlogp = (const float*)d_in[5];

  // ws layout (~74 MB; harness provided >= 75.5 MB in rounds 2-8)
  char* w = (char*)d_ws;
  double* acc = (double*)w;  // ctrl: acc(8) + nAlive(4) + flagbits(256)
  unsigned* nAlive = (unsigned*)(w + 8);
  unsigned* flagbits = (unsigned*)(w + 16);
  w += 512;
  unsigned* pkPre = (unsigned*)w;  // 512*2048*4 = 4 MB
  w += (size_t)MROWS * K_ * 4;
  float* P = (float*)w;  // 64*2048*4 = 512 KB each
  w += (size_t)MCH * K_ * 4;
  float* Zl = (float*)w;
  w += (size_t)MCH * K_ * 4;
  float* D0 = (float*)w;
  w += (size_t)MCH * K_ * 4;
  float* Ssuf = (float*)w;
  w += (size_t)MCH * K_ * 4;
  unsigned* pkFull = (unsigned*)w;  // 2048*8192*4 = 67 MB (fallback only)

  kPre<<<NBPRE, 256, 0, stream>>>(tsv, tev, r, ologp, tlogp, pkPre, P, Zl,
                                  acc, flagbits, nAlive);
  kScan<<<K_ / 256, 256, 0, stream>>>(P, Zl, D0, Ssuf, flagbits, nAlive);
  kApply<<<NBPRE + NBTAIL + NBC, 256, 0, stream>>>(
      sv, tsv, tev, r, ologp, tlogp, pkPre, D0, Ssuf, flagbits, nAlive,
      pkFull, acc);
  k4<<<1, 1, 0, stream>>>(acc, (float*)d_out);
}

// Round 10
// 48.188 us; speedup vs baseline: 7.8206x; 1.5994x over previous
//
#include <hip/hip_runtime.h>

// Retrace loss: T=8192, K=2048, gamma=0.99.
// decay = cumprod(gamma*iw); S = reverse-cumsum(td*decay);
// retrace = S / max(decay,1e-10); loss = mean(smooth_l1(q, retrace)).
//
// f32 decay underflows to EXACT 0 within ~170 rows for every column
// (E[ln c]=-0.574, sd 0.83/step; at row 512 log-decay = -294 +- 18.7 =>
// alive prob ~1e-24). Once decay==0, retrace==0 in both our and the
// reference's arithmetic (absmax 0.0, rounds 6-9).
//
// Structure lessons (hard-won):
//  R7: co-scheduling the latency-bound prefix chain with the tail BW flood
//      stretches the chain 5x. Keep kPre ALONE.
//  R8: __threadfence ticket in a wide grid = L2 writeback storm: 448us.
//  R9: f64 atomics on one address + ctrl fields on the SAME cacheline as
//      the flag reads = 50us of line ping-pong (duration identical for
//      HBM-cold and L3-resident passes = fixed-cost serialization).
// R10: ZERO atomics. kScan builds alive masks via __ballot (plain store);
//      every kApply block writes partials[bid]; k4 sums 2568 partials.
//      All ctrl arrays on separate pages. Fully deterministic.

#define GAMMA 0.99f

constexpr int T_ = 8192;
constexpr int K_ = 2048;
constexpr int N_ = T_ - 1;               // 8191
constexpr int MROWS = 512;               // exact-prefix length
constexpr int L_ = 8;                    // rows per chunk
constexpr int MCH = MROWS / L_;          // 64 chunks
constexpr int NBPRE = MCH * (K_ / 256);  // 512 blocks (kPre and role A)
constexpr int NBTAIL = 2048;             // role-B blocks
constexpr int NBC = K_ / 256;            // 8 role-C blocks
constexpr int NBTOT = NBPRE + NBTAIL + NBC;  // 2568
constexpr long long TAILF4 = (long long)(N_ - MROWS) * K_ / 4;  // 3,931,648

typedef float f4 __attribute__((ext_vector_type(4)));
typedef unsigned short us4 __attribute__((ext_vector_type(4)));

__device__ __forceinline__ unsigned short f2bf(float f) {  // RTNE
  unsigned u = __float_as_uint(f);
  u += 0x7FFFu + ((u >> 16) & 1u);
  return (unsigned short)(u >> 16);
}
__device__ __forceinline__ float bf2f(unsigned short h) {
  return __uint_as_float(((unsigned)h) << 16);
}
__device__ __forceinline__ float bfhi(unsigned q) {  // y in hi16
  return __uint_as_float(q & 0xFFFF0000u);
}
__device__ __forceinline__ float bflo(unsigned q) {  // ld in lo16
  return __uint_as_float(q << 16);
}
__device__ __forceinline__ float sl1(float dd) {
  float ad = fabsf(dd);
  return (ad < 1.f) ? 0.5f * dd * dd : ad - 0.5f;
}
// Block sum -> partials[bid] (plain store, no atomics).
__device__ __forceinline__ void block_reduce_store(float l, float* slot) {
  for (int off = 32; off > 0; off >>= 1) l += __shfl_down(l, off);
  __shared__ float wsum[4];
  const int lane = threadIdx.x & 63, wid = threadIdx.x >> 6;
  if (lane == 0) wsum[wid] = l;
  __syncthreads();
  if (threadIdx.x == 0) *slot = wsum[0] + wsum[1] + wsum[2] + wsum[3];
}

// ---------------------------------------------------------------- kPre
// 8x256 tile of rows [0,512). Grid: 512 blocks (chunk = bid>>3, colblock
// = bid&7). Phase 1: waves stream rows (depth-1 pipeline, no chain near
// loads); phase 2: per-column f32 chain, packed bf16 (y|ld) store +
// chunk summaries P, Zl. Numerics proven (absmax 0.0, R8/R9).
__global__ __launch_bounds__(256) void kPre(
    const float* __restrict__ tsv, const float* __restrict__ tev,
    const float* __restrict__ r, const float* __restrict__ ologp,
    const float* __restrict__ tlogp, unsigned* __restrict__ pkPre,
    float* __restrict__ P, float* __restrict__ Zl) {
  __shared__ float csh[L_][256];            // f32 c (exact chain)
  __shared__ unsigned short tdsh[L_][256];  // bf16 td
  const int tid = threadIdx.x;
  const int lane = tid & 63;
  const int wid = tid >> 6;
  const int c0 = (blockIdx.x & 7) * 256;
  const int chunk = blockIdx.x >> 3;
  const int i0 = chunk * L_;
  const int col = c0 + lane * 4;

  f4 lwA, aA, vA, rrA;
  float oA;
  auto issue = [&](int s, f4& lw, f4& a, f4& v, f4& rr, float& o) {
    const int i = i0 + s;
    const size_t b1 = (size_t)(i + 1) * K_ + col;
    const size_t b0 = (size_t)i * K_ + col;
    lw = *(const f4*)(tlogp + b1);
    a = *(const f4*)(tsv + b1);
    v = *(const f4*)(tev + b1);
    rr = *(const f4*)(r + b0);
    o = ologp[i + 1];
  };
  issue(wid, lwA, aA, vA, rrA, oA);
#pragma unroll
  for (int s0 = 0; s0 < L_; s0 += 4) {
    const int s = s0 + wid;
    f4 lwB, aB, vB, rrB;
    float oB;
    if (s0 + 4 < L_) issue(s + 4, lwB, aB, vB, rrB, oB);
    __builtin_amdgcn_sched_barrier(0);
    f4 iw, c, td;
#pragma unroll
    for (int x = 0; x < 4; ++x) iw[x] = __expf(fminf(lwA[x] - oA, 0.f));
#pragma unroll
    for (int x = 0; x < 4; ++x) c[x] = GAMMA * iw[x];
#pragma unroll
    for (int x = 0; x < 4; ++x)
      td[x] = fmaf(GAMMA, fmaf(-iw[x], aA[x], vA[x]), rrA[x]);
    *(f4*)&csh[s][lane * 4] = c;
    us4 t4;
#pragma unroll
    for (int x = 0; x < 4; ++x) t4[x] = f2bf(td[x]);
    *(us4*)&tdsh[s][lane * 4] = t4;
    if (s0 + 4 < L_) {
      lwA = lwB;
      aA = aB;
      vA = vB;
      rrA = rrB;
      oA = oB;
    }
  }
  __syncthreads();

  const int kcol = c0 + tid;
  float p = 1.f, zl = 0.f;
#pragma unroll
  for (int s = 0; s < L_; ++s) {
    p *= csh[s][tid];
    float y = bf2f(tdsh[s][tid]) * p;
    zl += y;
    pkPre[(size_t)(i0 + s) * K_ + kcol] = ((unsigned)f2bf(y) << 16) | f2bf(p);
  }
  P[(size_t)chunk * K_ + kcol] = p;
  Zl[(size_t)chunk * K_ + kcol] = zl;
}

// ---------------------------------------------------------------- kScan
// Per column: chunk prefix products D0, suffix sums Ssuf; per-wave ballot
// builds the alive bitmask (plain store, no atomics, no init needed).
__global__ __launch_bounds__(256) void kScan(
    const float* __restrict__ P, const float* __restrict__ Zl,
    float* __restrict__ D0, float* __restrict__ Ssuf,
    unsigned long long* __restrict__ flag64) {
  const int k = blockIdx.x * 256 + threadIdx.x;  // 0..K-1
  float d = 1.f;
#pragma unroll 16
  for (int c = 0; c < MCH; ++c) {
    D0[(size_t)c * K_ + k] = d;
    d *= P[(size_t)c * K_ + k];
  }
  const unsigned long long m = __ballot(d != 0.f);  // alive mask, 64 cols
  if ((threadIdx.x & 63) == 0) flag64[k >> 6] = m;
  float ss = 0.f;
#pragma unroll 16
  for (int c = MCH - 1; c >= 0; --c) {
    Ssuf[(size_t)c * K_ + k] = ss;
    ss = fmaf(D0[(size_t)c * K_ + k], Zl[(size_t)c * K_ + k], ss);
  }
}

// ---------------------------------------------------------------- kApply
// Role A: prefix apply (dead cols). Role B: tail sl1(sv) (dead cols).
// Role C: exact serial fallback per alive column (never for this data).
// Every block writes its own partials slot. NO atomics, NO fences.
__global__ __launch_bounds__(256) void kApply(
    const float* __restrict__ sv, const float* __restrict__ tsv,
    const float* __restrict__ tev, const float* __restrict__ r,
    const float* __restrict__ ologp, const float* __restrict__ tlogp,
    const unsigned* __restrict__ pkPre, const float* __restrict__ D0,
    const float* __restrict__ Ssuf,
    const unsigned long long* __restrict__ flag64,
    unsigned* __restrict__ pkFull, float* __restrict__ partials) {
  const int bid = blockIdx.x;
  const int tid = threadIdx.x;

  if (bid < NBPRE) {  // ---- role A: prefix rows [0,512)
    const int myc = bid >> 3;
    const int k = (bid & 7) * 256 + tid;
    float loss = 0.f;
    if (!((flag64[k >> 6] >> (k & 63)) & 1ull)) {
      const float d0 = D0[(size_t)myc * K_ + k];
      const float ssuf = Ssuf[(size_t)myc * K_ + k];
      const int i0 = myc * L_;
      float slocal = 0.f;
#pragma unroll
      for (int s = L_ - 1; s >= 0; --s) {
        const size_t b0 = (size_t)(i0 + s) * K_ + k;
        unsigned q = pkPre[b0];
        slocal += bfhi(q);
        float S = fmaf(d0, slocal, ssuf);
        float retrace = S / fmaxf(d0 * bflo(q), 1e-10f);
        loss += sl1(sv[b0] - retrace);
      }
    }
    block_reduce_store(loss, partials + bid);
  } else if (bid < NBPRE + NBTAIL) {  // ---- role B: tail rows [512,8191)
    __shared__ unsigned long long fb[32];
    __shared__ unsigned anyAlive;
    if (tid < 32) fb[tid] = flag64[tid];
    __syncthreads();
    if (tid == 0) {
      unsigned long long o = 0ull;
#pragma unroll
      for (int j = 0; j < 32; ++j) o |= fb[j];
      anyAlive = (o != 0ull) ? 1u : 0u;
    }
    __syncthreads();
    const long long base = (long long)MROWS * K_ / 4;  // f4 offset
    float loss = 0.f;
    if (anyAlive == 0u) {  // fast path: all columns dead
      for (long long v = (long long)(bid - NBPRE) * 256 + tid; v < TAILF4;
           v += (long long)NBTAIL * 256) {
        f4 q = ((const f4*)sv)[base + v];
#pragma unroll
        for (int x = 0; x < 4; ++x) loss += sl1(q[x]);
      }
    } else {
      for (long long v = (long long)(bid - NBPRE) * 256 + tid; v < TAILF4;
           v += (long long)NBTAIL * 256) {
        f4 q = ((const f4*)sv)[base + v];
        const int k0 = (int)((v * 4) & (K_ - 1));
#pragma unroll
        for (int x = 0; x < 4; ++x) {
          const int k = k0 + x;
          if (!((fb[k >> 6] >> (k & 63)) & 1ull)) loss += sl1(q[x]);
        }
      }
    }
    block_reduce_store(loss, partials + bid);
  } else {  // ---- role C: exact fallback, thread per column (rare/never)
    const int k = (bid - NBPRE - NBTAIL) * 256 + tid;
    float loss = 0.f;
    if ((flag64[k >> 6] >> (k & 63)) & 1ull) {
      unsigned* mycol = pkFull + (size_t)k * 8192;
      float p = 1.f;
      for (int i = 0; i < N_; ++i) {  // forward: exact sequential decay
        const size_t b1 = (size_t)(i + 1) * K_ + k;
        float iw = __expf(fminf(tlogp[b1] - ologp[i + 1], 0.f));
        p *= GAMMA * iw;
        float td =
            fmaf(GAMMA, fmaf(-iw, tsv[b1], tev[b1]), r[(size_t)i * K_ + k]);
        mycol[i] = ((unsigned)f2bf(td * p) << 16) | f2bf(p);
      }
      float slocal = 0.f;
      for (int i = N_ - 1; i >= 0; --i) {  // backward: S, loss, tail undo
        unsigned q = mycol[i];
        slocal += bfhi(q);
        float retrace = slocal / fmaxf(bflo(q), 1e-10f);
        float qv = sv[(size_t)i * K_ + k];
        loss += sl1(qv - retrace);
        if (i >= MROWS) loss -= sl1(qv);  // role B already added this
      }
      // role A skipped alive columns entirely, so no double count.
    }
    block_reduce_store(loss, partials + bid);
  }
}

// ---------------------------------------------------------------- k4
// Single block: f64 sum of the 2568 per-block partials, write mean.
__global__ __launch_bounds__(256) void k4(const float* __restrict__ partials,
                                          float* __restrict__ out) {
  double d = 0.0;
  for (int i = threadIdx.x; i < NBTOT; i += 256) d += (double)partials[i];
  for (int off = 32; off > 0; off >>= 1) d += __shfl_down(d, off);
  __shared__ double wsum[4];
  const int lane = threadIdx.x & 63, wid = threadIdx.x >> 6;
  if (lane == 0) wsum[wid] = d;
  __syncthreads();
  if (threadIdx.x == 0) {
    double s = wsum[0] + wsum[1] + wsum[2] + wsum[3];
    out[0] = (float)(s * (1.0 / ((double)N_ * (double)K_)));
  }
}

extern "C" void kernel_launch(void* const* d_in, const int* in_sizes, int n_in,
                              void* d_out, int out_size, void* d_ws,
                              size_t ws_size, hipStream_t stream) {
  const float* sv = (const float*)d_in[0];
  const float* tsv = (const float*)d_in[1];
  const float* tev = (const float*)d_in[2];
  const float* r = (const float*)d_in[3];
  const float* ologp = (const float*)d_in[4];
  const float* tlogp = (const float*)d_in[5];

  // ws layout (~74 MB; harness provided >= 75.5 MB in rounds 2-9).
  // Ctrl arrays on separate 4 KB pages (R9 lesson: no cacheline sharing).
  char* w = (char*)d_ws;
  unsigned long long* flag64 = (unsigned long long*)w;  // 32 u64, page 0
  float* partials = (float*)(w + 4096);                 // 2568 f32
  w += 4096 + 16384;
  unsigned* pkPre = (unsigned*)w;  // 512*2048*4 = 4 MB
  w += (size_t)MROWS * K_ * 4;
  float* P = (float*)w;  // 64*2048*4 = 512 KB each
  w += (size_t)MCH * K_ * 4;
  float* Zl = (float*)w;
  w += (size_t)MCH * K_ * 4;
  float* D0 = (float*)w;
  w += (size_t)MCH * K_ * 4;
  float* Ssuf = (float*)w;
  w += (size_t)MCH * K_ * 4;
  unsigned* pkFull = (unsigned*)w;  // 2048*8192*4 = 67 MB (fallback only)

  kPre<<<NBPRE, 256, 0, stream>>>(tsv, tev, r, ologp, tlogp, pkPre, P, Zl);
  kScan<<<K_ / 256, 256, 0, stream>>>(P, Zl, D0, Ssuf, flag64);
  kApply<<<NBTOT, 256, 0, stream>>>(sv, tsv, tev, r, ologp, tlogp, pkPre, D0,
                                    Ssuf, flag64, pkFull, partials);
  k4<<<1, 256, 0, stream>>>(partials, (float*)d_out);
}